// Round 1
// baseline (341.498 us; speedup 1.0000x reference)
//
#include <hip/hip_runtime.h>
#include <hip/hip_bf16.h>

typedef __attribute__((ext_vector_type(8))) short short8;
typedef __attribute__((ext_vector_type(4))) short bfx4;
typedef __attribute__((ext_vector_type(4))) float floatx4;
typedef __attribute__((ext_vector_type(4))) __fp16 h4_t;
typedef __attribute__((ext_vector_type(2))) __fp16 h2_t;
typedef __attribute__((ext_vector_type(8))) __fp16 h8_t;

#define BATCH 4
#define SEQ 2048
#define D_MODEL 1024
#define NH 16
#define HD 64
#define ELEMS 8388608   // B*S*D = 4*2048*1024
#define WELEMS 1048576  // 1024*1024

// fp32 -> bf16 round-to-nearest-even
__device__ __forceinline__ unsigned short f2bf(float f) {
    union { float f; unsigned u; } x; x.f = f;
    unsigned r = x.u + 0x7FFFu + ((x.u >> 16) & 1u);
    return (unsigned short)(r >> 16);
}
__device__ __forceinline__ unsigned short f2h(float f) {
    union { __fp16 h; unsigned short u; } x;
    x.h = (__fp16)f;
    return x.u;
}

#if __has_builtin(__builtin_amdgcn_exp2f)
__device__ __forceinline__ float fexp2(float x) { return __builtin_amdgcn_exp2f(x); }
#else
__device__ __forceinline__ float fexp2(float x) { return exp2f(x); }
#endif

// async global->LDS, 16B per lane; HW dest = wave-uniform base + lane*16
__device__ __forceinline__ void gll16(const void* g, const void* l) {
    __builtin_amdgcn_global_load_lds(
        (const __attribute__((address_space(1))) void*)g,
        (__attribute__((address_space(3))) void*)l,
        16, 0, 0);
}

#define BAR() __builtin_amdgcn_s_barrier()
#define WAIT_LGKM0() asm volatile("s_waitcnt lgkmcnt(0)" ::: "memory")
#define WAIT_VM(N) asm volatile("s_waitcnt vmcnt(" #N ")" ::: "memory")

// ---------------------------------------------------------------------------
// cvt: x (8M), wq|wk|wv (3M, concatenated), wo (1M) fp32 -> bf16
// ---------------------------------------------------------------------------
__global__ __launch_bounds__(256)
void cvt_kernel(const float* __restrict__ x,  const float* __restrict__ wq,
                const float* __restrict__ wk, const float* __restrict__ wv,
                const float* __restrict__ wo,
                unsigned short* __restrict__ xbf,
                unsigned short* __restrict__ wqkv,
                unsigned short* __restrict__ wobf)
{
    size_t idx = ((size_t)blockIdx.x * 256 + threadIdx.x) * 8;
    const float* src; unsigned short* dst; size_t off;
    if (idx < (size_t)ELEMS)                    { src = x;  dst = xbf;             off = idx; }
    else if (idx < (size_t)ELEMS + WELEMS)      { src = wq; dst = wqkv;            off = idx - ELEMS; }
    else if (idx < (size_t)ELEMS + 2 * WELEMS)  { src = wk; dst = wqkv + WELEMS;   off = idx - ELEMS - WELEMS; }
    else if (idx < (size_t)ELEMS + 3 * WELEMS)  { src = wv; dst = wqkv + 2*WELEMS; off = idx - ELEMS - 2*WELEMS; }
    else                                        { src = wo; dst = wobf;            off = idx - ELEMS - 3*WELEMS; }
    floatx4 a = *(const floatx4*)(src + off);
    floatx4 b = *(const floatx4*)(src + off + 4);
    short8 v;
#pragma unroll
    for (int d = 0; d < 4; d++) { v[d] = (short)f2bf(a[d]); v[4+d] = (short)f2bf(b[d]); }
    *(short8*)(dst + off) = v;
}

// ---------------------------------------------------------------------------
// 256x256 8-phase GEMM (T2 XOR-swizzle + T3/T4 counted-vmcnt pipeline + T5
// setprio), plain-HIP port of the m201-verified template.
//   A  [M,1024] bf16 row-major, Bw [N,1024] bf16 row-major (NT GEMM).
//   8 waves (2M x 4N), per-wave C = 128x64 (8 m-frags x 4 n-frags), BK=64.
//   LDS 128 KiB: double-buffered 256x64 A + 256x64 B tiles, linear layout,
//   staged via global_load_lds with inverse-swizzled global source (rule #21).
// Half-tile schedule (half = 128 rows, 2 gll16/thread): tile t's B halves
// staged during tile t-2 phases 2,3 (B reads of a tile finish at phase 1);
// A halves during tile t-1 phases 0,1 (A reads finish at phase 2). End-of-
// tile s_waitcnt vmcnt(4) drains exactly the next tile's 4 half-tiles while
// leaving the newest 2 (B of t+2) in flight — never vmcnt(0) mid-loop.
// MODE 0: scatter Q/K/V epilogue.  MODE 1: plain f32 output.
// ---------------------------------------------------------------------------
#define READ_A(MH, BUF)                                                          \
    do {                                                                         \
        _Pragma("unroll")                                                        \
        for (int mi_ = 0; mi_ < 4; mi_++) {                                      \
            _Pragma("unroll")                                                    \
            for (int c_ = 0; c_ < 2; c_++) {                                     \
                int ra_ = wm * 128 + ((MH) * 4 + mi_) * 16 + lm;                 \
                int g_ = c_ * 4 + lq;                                            \
                a[mi_][c_] = *(const short8*)(&As[BUF][(ra_ * 8 + (g_ ^ (ra_ & 7))) * 8]); \
            }                                                                    \
        }                                                                        \
    } while (0)

#define READ_B(NHF, BUF)                                                         \
    do {                                                                         \
        _Pragma("unroll")                                                        \
        for (int nj_ = 0; nj_ < 2; nj_++) {                                      \
            _Pragma("unroll")                                                    \
            for (int c_ = 0; c_ < 2; c_++) {                                     \
                int rb_ = wn * 64 + ((NHF) * 2 + nj_) * 16 + lm;                 \
                int g_ = c_ * 4 + lq;                                            \
                b[(NHF) * 2 + nj_][c_] = *(const short8*)(&Bs[BUF][(rb_ * 8 + (g_ ^ (rb_ & 7))) * 8]); \
            }                                                                    \
        }                                                                        \
    } while (0)

#define QUAD(MH, NHF)                                                            \
    do {                                                                         \
        __builtin_amdgcn_s_setprio(1);                                           \
        _Pragma("unroll")                                                        \
        for (int mi_ = 0; mi_ < 4; mi_++) {                                      \
            _Pragma("unroll")                                                    \
            for (int nj_ = 0; nj_ < 2; nj_++) {                                  \
                _Pragma("unroll")                                                \
                for (int c_ = 0; c_ < 2; c_++)                                   \
                    acc[(MH) * 4 + mi_][(NHF) * 2 + nj_] =                       \
                        __builtin_amdgcn_mfma_f32_16x16x32_bf16(                 \
                            a[mi_][c_], b[(NHF) * 2 + nj_][c_],                  \
                            acc[(MH) * 4 + mi_][(NHF) * 2 + nj_], 0, 0, 0);      \
            }                                                                    \
        }                                                                        \
        __builtin_amdgcn_s_setprio(0);                                           \
    } while (0)

// stage one half-tile (128 rows x 64 cols) for this wave: 2 x gll16.
// DSTBASE wave-uniform; global source pre-swizzled (lg^lrow) so linear LDS
// writes land in the swizzled layout the READ_* macros expect.
#define STAGE(DSTBASE, SRC, GROW0, KT)                                           \
    do {                                                                         \
        _Pragma("unroll")                                                        \
        for (int i_ = 0; i_ < 2; i_++) {                                         \
            int r8_ = wave * 16 + i_ * 8;                                        \
            gll16((SRC) + (size_t)((GROW0) + r8_ + lrow) * 1024 + (KT) * 64 + ((lg ^ lrow) << 3), \
                  (DSTBASE) + r8_ * 64);                                         \
        }                                                                        \
    } while (0)

template <int MODE>
__global__ __launch_bounds__(512, 2)
void gemm8_kernel(const unsigned short* __restrict__ A,
                  const unsigned short* __restrict__ Bw,
                  unsigned short* __restrict__ Qb,
                  unsigned short* __restrict__ Kb,
                  unsigned short* __restrict__ Vb,
                  float* __restrict__ Out)
{
    __shared__ __align__(16) unsigned short As[2][256 * 64];  // 64 KiB
    __shared__ __align__(16) unsigned short Bs[2][256 * 64];  // 64 KiB

    const int t = threadIdx.x;
    const int wave = t >> 6, lane = t & 63;
    const int lm = lane & 15, lq = lane >> 4;
    const int wm = wave >> 2, wn = wave & 3;
    const int lrow = lane >> 3, lg = lane & 7;
    const int m0 = blockIdx.x * 256, n0 = blockIdx.y * 256;

    floatx4 acc[8][4] = {};
    short8 a[4][2], b[4][2];

    // prologue: B0(0),B1(0),A0(0),A1(0),B0(1),B1(1); drain to tile-0-ready
    STAGE(&Bs[0][0],        Bw, n0,       0);
    STAGE(&Bs[0][128 * 64], Bw, n0 + 128, 0);
    STAGE(&As[0][0],        A,  m0,       0);
    STAGE(&As[0][128 * 64], A,  m0 + 128, 0);
    STAGE(&Bs[1][0],        Bw, n0,       1);
    STAGE(&Bs[1][128 * 64], Bw, n0 + 128, 1);
    WAIT_VM(4);
    BAR();

#pragma unroll 2
    for (int kt = 0; kt < 16; kt++) {
        const int cur = kt & 1, nxt = cur ^ 1;
        // ---- phase 0: read A(mh0)+B(nh0); stage A0(t+1) -> other buffer
        READ_A(0, cur); READ_B(0, cur);
        if (kt + 1 < 16) STAGE(&As[nxt][0], A, m0, kt + 1);
        BAR(); WAIT_LGKM0();
        QUAD(0, 0);
        BAR();
        // ---- phase 1: read B(nh1); stage A1(t+1)
        READ_B(1, cur);
        if (kt + 1 < 16) STAGE(&As[nxt][128 * 64], A, m0 + 128, kt + 1);
        BAR(); WAIT_LGKM0();
        QUAD(0, 1);
        BAR();
        // ---- phase 2: read A(mh1); B reads of this tile done -> stage B0(t+2)
        READ_A(1, cur);
        if (kt + 2 < 16) STAGE(&Bs[cur][0], Bw, n0, kt + 2);
        BAR(); WAIT_LGKM0();
        QUAD(1, 0);
        BAR();
        // ---- phase 3: no reads; stage B1(t+2); counted vmcnt drains t+1
        if (kt + 2 < 16) STAGE(&Bs[cur][128 * 64], Bw, n0 + 128, kt + 2);
        BAR();
        QUAD(1, 1);
        if (kt + 2 < 16) { WAIT_VM(4); } else { WAIT_VM(0); }
        BAR();
    }

    if (MODE == 0) {
        const int z = n0 >> 10;   // 0=Q 1=K 2=V, uniform per block (1024%256==0)
#pragma unroll
        for (int mi = 0; mi < 8; mi++)
#pragma unroll
            for (int nj = 0; nj < 4; nj++)
#pragma unroll
                for (int r = 0; r < 4; r++) {
                    int gm = m0 + wm * 128 + mi * 16 + lq * 4 + r;
                    int gn = n0 + wn * 64 + nj * 16 + lm;
                    int nl = gn & 1023, h = nl >> 6, d = nl & 63;
                    int bb = gm >> 11, s = gm & 2047;
                    float v = acc[mi][nj][r];
                    size_t bh = (size_t)(bb * NH + h);
                    if (z == 0)      Qb[(bh * SEQ + s) * HD + d] = f2bf(v);
                    else if (z == 1) Kb[(bh * SEQ + s) * HD + d] = f2bf(v);
                    else             Vb[(bh * HD + d) * SEQ + s] = f2h(v);
                }
    } else {
#pragma unroll
        for (int mi = 0; mi < 8; mi++)
#pragma unroll
            for (int nj = 0; nj < 4; nj++)
#pragma unroll
                for (int r = 0; r < 4; r++) {
                    int gm = m0 + wm * 128 + mi * 16 + lq * 4 + r;
                    int gn = n0 + wn * 64 + nj * 16 + lm;
                    Out[(size_t)gm * D_MODEL + gn] = acc[mi][nj][r];
                }
    }
}

// ---------------------------------------------------------------------------
// Flash attention v5 (unchanged): balanced paired q-tiles (j,31-j), no-max
// softmax, streamed sub-tiles. Q,K bf16 [b,h,s,d]; V f16 [b,h,d,s];
// O bf16 [b,s,1024]. Row 2047 (l=0) fixed by row2047_kernel afterwards.
// ---------------------------------------------------------------------------
#define PROCESS_Q(QI, BQ, ACC, LACC, DOMASK, KT)                               \
    do {                                                                       \
        _Pragma("unroll")                                                      \
        for (int jt = 0; jt < 8; jt++) {                                       \
            floatx4 sc = {};                                                   \
            _Pragma("unroll")                                                  \
            for (int c = 0; c < 2; c++) {                                      \
                int row_ = jt * 16 + lm;                                       \
                int g_ = c * 4 + lq;                                           \
                short8 kf = *(const short8*)(Ks + (row_ * 8 + (g_ ^ (row_ & 7))) * 8); \
                sc = __builtin_amdgcn_mfma_f32_16x16x32_bf16(kf, BQ[c], sc, 0, 0, 0); \
            }                                                                  \
            if (DOMASK) {                                                      \
                _Pragma("unroll")                                              \
                for (int r = 0; r < 4; r++) {                                  \
                    int kj = (KT) * 128 + jt * 16 + lq * 4 + r;                \
                    if (!(kj > (QI))) sc[r] = -3.2e10f;                        \
                }                                                              \
            }                                                                  \
            float p0 = fexp2(sc[0] * kA), p1 = fexp2(sc[1] * kA);              \
            float p2 = fexp2(sc[2] * kA), p3 = fexp2(sc[3] * kA);              \
            LACC += (p0 + p1) + (p2 + p3);                                     \
            h2_t a01 = __builtin_amdgcn_cvt_pkrtz(p0, p1);                     \
            h2_t a23 = __builtin_amdgcn_cvt_pkrtz(p2, p3);                     \
            h4_t pf;                                                           \
            pf[0] = a01[0]; pf[1] = a01[1]; pf[2] = a23[0]; pf[3] = a23[1];    \
            _Pragma("unroll")                                                  \
            for (int jd = 0; jd < 4; jd++) {                                   \
                int rowv_ = jd * 16 + lm;                                      \
                int g16_ = jt * 2 + (lq >> 1);                                 \
                int slot_ = rowv_ * 16 + (g16_ ^ lm);                          \
                h4_t vf = *(const h4_t*)((const __fp16*)Vs + slot_ * 8 + (lq & 1) * 4); \
                ACC[jd] = __builtin_amdgcn_mfma_f32_16x16x16f16(vf, pf, ACC[jd], 0, 0, 0); \
            }                                                                  \
        }                                                                      \
    } while (0)

__global__ __launch_bounds__(256, 2)
void attn5_kernel(const unsigned short* __restrict__ Q,
                  const unsigned short* __restrict__ K,
                  const unsigned short* __restrict__ V,
                  unsigned short* __restrict__ O)
{
    __shared__ __align__(16) unsigned short Ks[128 * 64];  // [key][d] swizzled bf16
    __shared__ __align__(16) unsigned short Vs[64 * 128];  // [d][key] swizzled f16

    const int t = threadIdx.x;
    const int wave = t >> 6, lane = t & 63;
    const int lm = lane & 15, lq = lane >> 4;
    const int bh = blockIdx.y;
    const int jlo = blockIdx.x, jhi = 31 - jlo;
    const int qlo = jlo * 64 + wave * 16 + lm;
    const int qhi = jhi * 64 + wave * 16 + lm;

    const unsigned short* Qh = Q + (size_t)bh * SEQ * HD;
    const unsigned short* Kh = K + (size_t)bh * SEQ * HD;
    const unsigned short* Vh = V + (size_t)bh * HD * SEQ;  // [d][s]

    short8 bq_lo[2], bq_hi[2];
    bq_lo[0] = *(const short8*)(Qh + (size_t)qlo * HD + lq * 8);
    bq_lo[1] = *(const short8*)(Qh + (size_t)qlo * HD + 32 + lq * 8);
    bq_hi[0] = *(const short8*)(Qh + (size_t)qhi * HD + lq * 8);
    bq_hi[1] = *(const short8*)(Qh + (size_t)qhi * HD + 32 + lq * 8);

    floatx4 acc_lo[4] = {}, acc_hi[4] = {};
    float l_lo = 0.f, l_hi = 0.f;
    const float kA = 0.04508422002778011f;  // log2(e)/32

    const int lrow = lane >> 3, lg = lane & 7;
    const int kt_min = jlo >> 1;
    const int kthi_min = 15 - kt_min;

    for (int kt = 15; kt >= kt_min; kt--) {
        __syncthreads();
        // K tile: 128 keys x 64 d
#pragma unroll
        for (int i = 0; i < 4; i++) {
            int rows8 = wave * 32 + i * 8;
            gll16(Kh + (size_t)(kt * 128 + rows8 + lrow) * HD + (lg ^ lrow) * 8,
                  Ks + rows8 * 64);
        }
        // V^T tile: 64 d x 128 keys
#pragma unroll
        for (int i = 0; i < 4; i++) {
            int rows4 = wave * 16 + i * 4;
            int row = rows4 + (lane >> 4);
            int g = (lane & 15) ^ (row & 15);
            gll16(Vh + (size_t)row * SEQ + kt * 128 + g * 8, Vs + rows4 * 128);
        }
        __syncthreads();

        PROCESS_Q(qlo, bq_lo, acc_lo, l_lo, (kt == kt_min), kt);
        if (kt >= kthi_min)
            PROCESS_Q(qhi, bq_hi, acc_hi, l_hi, (kt == kthi_min), kt);
    }

    const int b = bh >> 4, h = bh & 15;
    {
        float l = l_lo;
        l += __shfl_xor(l, 16); l += __shfl_xor(l, 32);
        float inv = 1.0f / l;
#pragma unroll
        for (int jd = 0; jd < 4; jd++) {
            bfx4 o;
#pragma unroll
            for (int r = 0; r < 4; r++) o[r] = (short)f2bf(acc_lo[jd][r] * inv);
            *(bfx4*)(O + (size_t)(b * SEQ + qlo) * D_MODEL + h * HD + jd * 16 + lq * 4) = o;
        }
    }
    {
        float l = l_hi;
        l += __shfl_xor(l, 16); l += __shfl_xor(l, 32);
        float inv = 1.0f / l;
#pragma unroll
        for (int jd = 0; jd < 4; jd++) {
            bfx4 o;
#pragma unroll
            for (int r = 0; r < 4; r++) o[r] = (short)f2bf(acc_hi[jd][r] * inv);
            *(bfx4*)(O + (size_t)(b * SEQ + qhi) * D_MODEL + h * HD + jd * 16 + lq * 4) = o;
        }
    }
}

// ---------------------------------------------------------------------------
// Row 2047 is fully masked -> uniform softmax over ALL keys -> mean of V.
// ---------------------------------------------------------------------------
__global__ __launch_bounds__(256, 2)
void row2047_kernel(const unsigned short* __restrict__ V,
                    unsigned short* __restrict__ O)
{
    __shared__ float red[256];
    const int bh = blockIdx.x;
    const int b = bh >> 4, h = bh & 15;
    const int t = threadIdx.x;
    const int d = t & 63, seg = t >> 6;
    const __fp16* Vh = (const __fp16*)V + (size_t)bh * HD * SEQ + (size_t)d * SEQ + seg * 512;
    float s = 0.f;
    for (int i = 0; i < 512; i += 8) {
        h8_t v = *(const h8_t*)(Vh + i);
#pragma unroll
        for (int j = 0; j < 8; j++) s += (float)v[j];
    }
    red[t] = s;
    __syncthreads();
    if (seg == 0) {
        float tot = red[d] + red[64 + d] + red[128 + d] + red[192 + d];
        O[(size_t)(b * SEQ + 2047) * D_MODEL + h * HD + d] = f2bf(tot * (1.f / 2048.f));
    }
}

// ======================= fallback (ws < 72 MiB) kernels =====================
__global__ __launch_bounds__(256, 2)
void gemm_qkv_kernel(const float* __restrict__ A,
                     const float* __restrict__ W0,
                     const float* __restrict__ W1,
                     const float* __restrict__ W2,
                     unsigned short* __restrict__ O0,
                     unsigned short* __restrict__ O1,
                     unsigned short* __restrict__ O2)
{
    const int K = 1024;
    const float* W;
    unsigned short* Out;
    if (blockIdx.z == 0)      { W = W0; Out = O0; }
    else if (blockIdx.z == 1) { W = W1; Out = O1; }
    else                      { W = W2; Out = O2; }

    __shared__ __align__(16) unsigned short As[128 * 64];
    __shared__ __align__(16) unsigned short Bs[128 * 64];

    const int t = threadIdx.x;
    const int wave = t >> 6, lane = t & 63;
    const int lm = lane & 15, lq = lane >> 4;
    const int wrow = (wave >> 1) * 64, wcol = (wave & 1) * 64;
    const int m0 = blockIdx.x * 128, n0 = blockIdx.y * 128;

    floatx4 acc[4][4] = {};

    for (int k0 = 0; k0 < K; k0 += 64) {
        __syncthreads();
#pragma unroll
        for (int rr = 0; rr < 4; rr++) {
            int p = rr * 256 + t;
            int row = p >> 3, g = p & 7;
            const float* pa = A + (size_t)(m0 + row) * K + k0 + g * 8;
            const float* pw = W + (size_t)(n0 + row) * K + k0 + g * 8;
            floatx4 a0 = *(const floatx4*)pa, a1 = *(const floatx4*)(pa + 4);
            floatx4 w0 = *(const floatx4*)pw, w1 = *(const floatx4*)(pw + 4);
            short8 va, vb;
#pragma unroll
            for (int d = 0; d < 4; d++) {
                va[d]     = (short)f2bf(a0[d]);
                va[4 + d] = (short)f2bf(a1[d]);
                vb[d]     = (short)f2bf(w0[d]);
                vb[4 + d] = (short)f2bf(w1[d]);
            }
            int dst = row * 8 + (g ^ (row & 7));
            *(short8*)(As + dst * 8) = va;
            *(short8*)(Bs + dst * 8) = vb;
        }
        __syncthreads();

        short8 af[4][2], bf[4][2];
#pragma unroll
        for (int i = 0; i < 4; i++)
#pragma unroll
            for (int c = 0; c < 2; c++) {
                int ra = wrow + i * 16 + lm;
                int rb = wcol + i * 16 + lm;
                int g = c * 4 + lq;
                af[i][c] = *(const short8*)(As + (ra * 8 + (g ^ (ra & 7))) * 8);
                bf[i][c] = *(const short8*)(Bs + (rb * 8 + (g ^ (rb & 7))) * 8);
            }
#pragma unroll
        for (int i = 0; i < 4; i++)
#pragma unroll
            for (int j = 0; j < 4; j++)
#pragma unroll
                for (int c = 0; c < 2; c++)
                    acc[i][j] = __builtin_amdgcn_mfma_f32_16x16x32_bf16(
                        af[i][c], bf[j][c], acc[i][j], 0, 0, 0);
    }

    const int zi = blockIdx.z;
#pragma unroll
    for (int i = 0; i < 4; i++)
#pragma unroll
        for (int j = 0; j < 4; j++)
#pragma unroll
            for (int r = 0; r < 4; r++) {
                int gm = m0 + wrow + i * 16 + lq * 4 + r;
                int gn = n0 + wcol + j * 16 + lm;
                int b = gm >> 11, s = gm & 2047;
                int h = gn >> 6, d = gn & 63;
                if (zi == 2) {
                    Out[((size_t)(b * NH + h) * HD + d) * SEQ + s] = f2h(acc[i][j][r]);
                } else {
                    Out[((size_t)(b * NH + h) * SEQ + s) * HD + d] = f2bf(acc[i][j][r]);
                }
            }
}

__global__ __launch_bounds__(256, 2)
void gemm_out_kernel(const unsigned short* __restrict__ Abf,
                     const float* __restrict__ W,
                     float* __restrict__ Out)
{
    const int K = 1024;
    __shared__ __align__(16) unsigned short As[128 * 64];
    __shared__ __align__(16) unsigned short Bs[128 * 64];

    const int t = threadIdx.x;
    const int wave = t >> 6, lane = t & 63;
    const int lm = lane & 15, lq = lane >> 4;
    const int wrow = (wave >> 1) * 64, wcol = (wave & 1) * 64;
    const int m0 = blockIdx.x * 128, n0 = blockIdx.y * 128;

    floatx4 acc[4][4] = {};

    for (int k0 = 0; k0 < K; k0 += 64) {
        __syncthreads();
#pragma unroll
        for (int rr = 0; rr < 4; rr++) {
            int p = rr * 256 + t;
            int row = p >> 3, g = p & 7;
            short8 va = *(const short8*)(Abf + (size_t)(m0 + row) * K + k0 + g * 8);
            const float* pw = W + (size_t)(n0 + row) * K + k0 + g * 8;
            floatx4 w0 = *(const floatx4*)pw, w1 = *(const floatx4*)(pw + 4);
            short8 vb;
#pragma unroll
            for (int d = 0; d < 4; d++) {
                vb[d]     = (short)f2bf(w0[d]);
                vb[4 + d] = (short)f2bf(w1[d]);
            }
            int dst = row * 8 + (g ^ (row & 7));
            *(short8*)(As + dst * 8) = va;
            *(short8*)(Bs + dst * 8) = vb;
        }
        __syncthreads();

        short8 af[4][2], bf[4][2];
#pragma unroll
        for (int i = 0; i < 4; i++)
#pragma unroll
            for (int c = 0; c < 2; c++) {
                int ra = wrow + i * 16 + lm;
                int rb = wcol + i * 16 + lm;
                int g = c * 4 + lq;
                af[i][c] = *(const short8*)(As + (ra * 8 + (g ^ (ra & 7))) * 8);
                bf[i][c] = *(const short8*)(Bs + (rb * 8 + (g ^ (rb & 7))) * 8);
            }
#pragma unroll
        for (int i = 0; i < 4; i++)
#pragma unroll
            for (int j = 0; j < 4; j++)
#pragma unroll
                for (int c = 0; c < 2; c++)
                    acc[i][j] = __builtin_amdgcn_mfma_f32_16x16x32_bf16(
                        af[i][c], bf[j][c], acc[i][j], 0, 0, 0);
    }

#pragma unroll
    for (int i = 0; i < 4; i++)
#pragma unroll
        for (int j = 0; j < 4; j++)
#pragma unroll
            for (int r = 0; r < 4; r++) {
                int gm = m0 + wrow + i * 16 + lq * 4 + r;
                int gn = n0 + wcol + j * 16 + lm;
                Out[(size_t)gm * D_MODEL + gn] = acc[i][j][r];
            }
}

extern "C" void kernel_launch(void* const* d_in, const int* in_sizes, int n_in,
                              void* d_out, int out_size, void* d_ws, size_t ws_size,
                              hipStream_t stream) {
    const float* x  = (const float*)d_in[0];
    const float* wq = (const float*)d_in[1];
    const float* wk = (const float*)d_in[2];
    const float* wv = (const float*)d_in[3];
    const float* wo = (const float*)d_in[4];

    unsigned short* ws = (unsigned short*)d_ws;
    const bool fast = ws_size >= (size_t)36 * 1024 * 1024 * 2;  // 72 MiB

    if (fast) {
        unsigned short* xbf  = ws;                     // 8M elems; reused as Ob
        unsigned short* wqkv = ws + (size_t)ELEMS;     // 3M
        unsigned short* wobf = ws + (size_t)ELEMS + 3 * WELEMS;  // 1M
        unsigned short* Qb   = ws + (size_t)ELEMS + 4 * WELEMS;  // 8M
        unsigned short* Kb   = Qb + ELEMS;
        unsigned short* Vb   = Kb + ELEMS;
        unsigned short* Ob   = xbf;                    // x_bf dead after QKV GEMM

        cvt_kernel<<<6144, 256, 0, stream>>>(x, wq, wk, wv, wo, xbf, wqkv, wobf);
        gemm8_kernel<0><<<dim3(32, 12), 512, 0, stream>>>(xbf, wqkv, Qb, Kb, Vb, nullptr);
        attn5_kernel<<<dim3(16, BATCH * NH), 256, 0, stream>>>(Qb, Kb, Vb, Ob);
        row2047_kernel<<<BATCH * NH, 256, 0, stream>>>(Vb, Ob);
        gemm8_kernel<1><<<dim3(32, 4), 512, 0, stream>>>(Ob, wobf, nullptr, nullptr, nullptr, (float*)d_out);
    } else {
        unsigned short* Qb = ws;
        unsigned short* Kb = Qb + ELEMS;
        unsigned short* Vb = Kb + ELEMS;
        unsigned short* Ob = Vb + ELEMS;

        gemm_qkv_kernel<<<dim3(64, 8, 3), 256, 0, stream>>>(x, wq, wk, wv, Qb, Kb, Vb);
        attn5_kernel<<<dim3(16, BATCH * NH), 256, 0, stream>>>(Qb, Kb, Vb, Ob);
        row2047_kernel<<<BATCH * NH, 256, 0, stream>>>(Vb, Ob);
        gemm_out_kernel<<<dim3(64, 8), 256, 0, stream>>>(Ob, wo, (float*)d_out);
    }
}

// Round 2
// 336.938 us; speedup vs baseline: 1.0135x; 1.0135x over previous
//
#include <hip/hip_runtime.h>
#include <hip/hip_bf16.h>

typedef __attribute__((ext_vector_type(8))) short short8;
typedef __attribute__((ext_vector_type(4))) short bfx4;
typedef __attribute__((ext_vector_type(4))) float floatx4;
typedef __attribute__((ext_vector_type(4))) __fp16 h4_t;
typedef __attribute__((ext_vector_type(2))) __fp16 h2_t;
typedef __attribute__((ext_vector_type(8))) __fp16 h8_t;

#define BATCH 4
#define SEQ 2048
#define D_MODEL 1024
#define NH 16
#define HD 64
#define ELEMS 8388608   // B*S*D = 4*2048*1024
#define WELEMS 1048576  // 1024*1024

// fp32 -> bf16 round-to-nearest-even
__device__ __forceinline__ unsigned short f2bf(float f) {
    union { float f; unsigned u; } x; x.f = f;
    unsigned r = x.u + 0x7FFFu + ((x.u >> 16) & 1u);
    return (unsigned short)(r >> 16);
}
__device__ __forceinline__ unsigned short f2h(float f) {
    union { __fp16 h; unsigned short u; } x;
    x.h = (__fp16)f;
    return x.u;
}

#if __has_builtin(__builtin_amdgcn_exp2f)
__device__ __forceinline__ float fexp2(float x) { return __builtin_amdgcn_exp2f(x); }
#else
__device__ __forceinline__ float fexp2(float x) { return exp2f(x); }
#endif

// async global->LDS, 16B per lane; HW dest = wave-uniform base + lane*16
__device__ __forceinline__ void gll16(const void* g, const void* l) {
    __builtin_amdgcn_global_load_lds(
        (const __attribute__((address_space(1))) void*)g,
        (__attribute__((address_space(3))) void*)l,
        16, 0, 0);
}

// NOTE (R1 post-mortem): an 8-phase 256^2 counted-vmcnt port (gemm8) was tried
// and REGRESSED the total 317->341 us: grid geometry at 256^2 (384 blocks =
// 1.5 rounds for QKV, 128 blocks = half machine for Wo) plus an unverified
// schedule port. Reverted to these proven kernels. Do not re-attempt without
// per-kernel timing evidence for the GEMM dispatches.

// ---------------------------------------------------------------------------
// cvt: x (8M), wq|wk|wv (3M, concatenated), wo (1M) fp32 -> bf16
// ---------------------------------------------------------------------------
__global__ __launch_bounds__(256)
void cvt_kernel(const float* __restrict__ x,  const float* __restrict__ wq,
                const float* __restrict__ wk, const float* __restrict__ wv,
                const float* __restrict__ wo,
                unsigned short* __restrict__ xbf,
                unsigned short* __restrict__ wqkv,
                unsigned short* __restrict__ wobf)
{
    size_t idx = ((size_t)blockIdx.x * 256 + threadIdx.x) * 8;
    const float* src; unsigned short* dst; size_t off;
    if (idx < (size_t)ELEMS)                    { src = x;  dst = xbf;             off = idx; }
    else if (idx < (size_t)ELEMS + WELEMS)      { src = wq; dst = wqkv;            off = idx - ELEMS; }
    else if (idx < (size_t)ELEMS + 2 * WELEMS)  { src = wk; dst = wqkv + WELEMS;   off = idx - ELEMS - WELEMS; }
    else if (idx < (size_t)ELEMS + 3 * WELEMS)  { src = wv; dst = wqkv + 2*WELEMS; off = idx - ELEMS - 2*WELEMS; }
    else                                        { src = wo; dst = wobf;            off = idx - ELEMS - 3*WELEMS; }
    floatx4 a = *(const floatx4*)(src + off);
    floatx4 b = *(const floatx4*)(src + off + 4);
    short8 v;
#pragma unroll
    for (int d = 0; d < 4; d++) { v[d] = (short)f2bf(a[d]); v[4+d] = (short)f2bf(b[d]); }
    *(short8*)(dst + off) = v;
}

// ---------------------------------------------------------------------------
// Fast QKV GEMM: A=x_bf [8192,1024], B=wqkv_bf [3072,1024] (NT), both staged
// via global_load_lds with inverse-XOR-swizzled source addressing.
// 128x256 tile, BK=64. Epilogue scatters Q/K/V (z uniform per block).
// ---------------------------------------------------------------------------
__global__ __launch_bounds__(256, 2)
void gemm_qkv2_kernel(const unsigned short* __restrict__ A,
                      const unsigned short* __restrict__ B,
                      unsigned short* __restrict__ Qb,
                      unsigned short* __restrict__ Kb,
                      unsigned short* __restrict__ Vb)
{
    __shared__ __align__(16) unsigned short As[128 * 64];
    __shared__ __align__(16) unsigned short Bs[256 * 64];

    const int t = threadIdx.x;
    const int wave = t >> 6, lane = t & 63;
    const int lm = lane & 15, lq = lane >> 4;
    const int wrow = (wave >> 1) * 64, wcol = (wave & 1) * 128;
    const int m0 = blockIdx.x * 128, n0 = blockIdx.y * 256;
    const int lrow = lane >> 3, lg = lane & 7;
    const int gsw = lg ^ lrow;

    floatx4 acc[4][8] = {};

    for (int k0 = 0; k0 < 1024; k0 += 64) {
        __syncthreads();
#pragma unroll
        for (int i = 0; i < 4; i++) {
            int rows8 = wave * 32 + i * 8;
            gll16(A + (size_t)(m0 + rows8 + lrow) * 1024 + k0 + gsw * 8, As + rows8 * 64);
        }
#pragma unroll
        for (int i = 0; i < 8; i++) {
            int rows8 = wave * 64 + i * 8;
            gll16(B + (size_t)(n0 + rows8 + lrow) * 1024 + k0 + gsw * 8, Bs + rows8 * 64);
        }
        __syncthreads();

#pragma unroll
        for (int c = 0; c < 2; c++) {
            short8 af[4], bfr[8];
#pragma unroll
            for (int i = 0; i < 4; i++) {
                int ra = wrow + i * 16 + lm;
                int g = c * 4 + lq;
                af[i] = *(const short8*)(As + (ra * 8 + (g ^ (ra & 7))) * 8);
            }
#pragma unroll
            for (int j = 0; j < 8; j++) {
                int rb = wcol + j * 16 + lm;
                int g = c * 4 + lq;
                bfr[j] = *(const short8*)(Bs + (rb * 8 + (g ^ (rb & 7))) * 8);
            }
#pragma unroll
            for (int i = 0; i < 4; i++)
#pragma unroll
                for (int j = 0; j < 8; j++)
                    acc[i][j] = __builtin_amdgcn_mfma_f32_16x16x32_bf16(
                        af[i], bfr[j], acc[i][j], 0, 0, 0);
        }
    }

    const int z = n0 >> 10;   // 0=Q 1=K 2=V, uniform per block
#pragma unroll
    for (int i = 0; i < 4; i++)
#pragma unroll
        for (int j = 0; j < 8; j++)
#pragma unroll
            for (int r = 0; r < 4; r++) {
                int gm = m0 + wrow + i * 16 + lq * 4 + r;
                int gn = n0 + wcol + j * 16 + lm;
                int nl = gn & 1023, h = nl >> 6, d = nl & 63;
                int b = gm >> 11, s = gm & 2047;
                float v = acc[i][j][r];
                size_t bh = (size_t)(b * NH + h);
                if (z == 0)      Qb[(bh * SEQ + s) * HD + d] = f2bf(v);
                else if (z == 1) Kb[(bh * SEQ + s) * HD + d] = f2bf(v);
                else             Vb[(bh * HD + d) * SEQ + s] = f2h(v);
            }
}

// ---------------------------------------------------------------------------
// Fast output projection: A=Ob bf16 [8192,1024], B=wo_bf [1024,1024] -> fp32
// ---------------------------------------------------------------------------
__global__ __launch_bounds__(256, 2)
void gemm_out2_kernel(const unsigned short* __restrict__ A,
                      const unsigned short* __restrict__ B,
                      float* __restrict__ Out)
{
    __shared__ __align__(16) unsigned short As[128 * 64];
    __shared__ __align__(16) unsigned short Bs[256 * 64];

    const int t = threadIdx.x;
    const int wave = t >> 6, lane = t & 63;
    const int lm = lane & 15, lq = lane >> 4;
    const int wrow = (wave >> 1) * 64, wcol = (wave & 1) * 128;
    const int m0 = blockIdx.x * 128, n0 = blockIdx.y * 256;
    const int lrow = lane >> 3, lg = lane & 7;
    const int gsw = lg ^ lrow;

    floatx4 acc[4][8] = {};

    for (int k0 = 0; k0 < 1024; k0 += 64) {
        __syncthreads();
#pragma unroll
        for (int i = 0; i < 4; i++) {
            int rows8 = wave * 32 + i * 8;
            gll16(A + (size_t)(m0 + rows8 + lrow) * 1024 + k0 + gsw * 8, As + rows8 * 64);
        }
#pragma unroll
        for (int i = 0; i < 8; i++) {
            int rows8 = wave * 64 + i * 8;
            gll16(B + (size_t)(n0 + rows8 + lrow) * 1024 + k0 + gsw * 8, Bs + rows8 * 64);
        }
        __syncthreads();

#pragma unroll
        for (int c = 0; c < 2; c++) {
            short8 af[4], bfr[8];
#pragma unroll
            for (int i = 0; i < 4; i++) {
                int ra = wrow + i * 16 + lm;
                int g = c * 4 + lq;
                af[i] = *(const short8*)(As + (ra * 8 + (g ^ (ra & 7))) * 8);
            }
#pragma unroll
            for (int j = 0; j < 8; j++) {
                int rb = wcol + j * 16 + lm;
                int g = c * 4 + lq;
                bfr[j] = *(const short8*)(Bs + (rb * 8 + (g ^ (rb & 7))) * 8);
            }
#pragma unroll
            for (int i = 0; i < 4; i++)
#pragma unroll
                for (int j = 0; j < 8; j++)
                    acc[i][j] = __builtin_amdgcn_mfma_f32_16x16x32_bf16(
                        af[i], bfr[j], acc[i][j], 0, 0, 0);
        }
    }

#pragma unroll
    for (int i = 0; i < 4; i++)
#pragma unroll
        for (int j = 0; j < 8; j++)
#pragma unroll
            for (int r = 0; r < 4; r++) {
                int gm = m0 + wrow + i * 16 + lq * 4 + r;
                int gn = n0 + wcol + j * 16 + lm;
                Out[(size_t)gm * D_MODEL + gn] = acc[i][j][r];
            }
}

// ---------------------------------------------------------------------------
// Flash attention v6: algorithm of v5 (balanced paired q-tiles (j,31-j),
// no-max softmax, streamed sub-tiles) + DOUBLE-BUFFERED K/V LDS with the
// stage for tile kt-1 ISSUED BEFORE the compute on tile kt, and a single
// __syncthreads() per iteration as the one drain point (its implicit
// vmcnt(0) lands after compute has covered the ~600-900 cyc stage latency).
// This removes the per-iteration full drain-before-compute of v5 (T3-minimum
// + T14 async-stage; m214 r277 measured +17% on this move).
// LDS 64 KiB -> still 2 blocks/CU.
// Q,K bf16 [b,h,s,d]; V f16 [b,h,d,s]; O bf16 [b,s,1024].
// Row 2047 (l=0) fixed by row2047_kernel afterwards.
// ---------------------------------------------------------------------------
#define PROCESS_Q(QI, BQ, ACC, LACC, DOMASK, KT)                               \
    do {                                                                       \
        _Pragma("unroll")                                                      \
        for (int jt = 0; jt < 8; jt++) {                                       \
            floatx4 sc = {};                                                   \
            _Pragma("unroll")                                                  \
            for (int c = 0; c < 2; c++) {                                      \
                int row_ = jt * 16 + lm;                                       \
                int g_ = c * 4 + lq;                                           \
                short8 kf = *(const short8*)(Ksb + (row_ * 8 + (g_ ^ (row_ & 7))) * 8); \
                sc = __builtin_amdgcn_mfma_f32_16x16x32_bf16(kf, BQ[c], sc, 0, 0, 0); \
            }                                                                  \
            if (DOMASK) {                                                      \
                _Pragma("unroll")                                              \
                for (int r = 0; r < 4; r++) {                                  \
                    int kj = (KT) * 128 + jt * 16 + lq * 4 + r;                \
                    if (!(kj > (QI))) sc[r] = -3.2e10f;                        \
                }                                                              \
            }                                                                  \
            float p0 = fexp2(sc[0] * kA), p1 = fexp2(sc[1] * kA);              \
            float p2 = fexp2(sc[2] * kA), p3 = fexp2(sc[3] * kA);              \
            LACC += (p0 + p1) + (p2 + p3);                                     \
            h2_t a01 = __builtin_amdgcn_cvt_pkrtz(p0, p1);                     \
            h2_t a23 = __builtin_amdgcn_cvt_pkrtz(p2, p3);                     \
            h4_t pf;                                                           \
            pf[0] = a01[0]; pf[1] = a01[1]; pf[2] = a23[0]; pf[3] = a23[1];    \
            _Pragma("unroll")                                                  \
            for (int jd = 0; jd < 4; jd++) {                                   \
                int rowv_ = jd * 16 + lm;                                      \
                int g16_ = jt * 2 + (lq >> 1);                                 \
                int slot_ = rowv_ * 16 + (g16_ ^ lm);                          \
                h4_t vf = *(const h4_t*)(Vsb + slot_ * 8 + (lq & 1) * 4);      \
                ACC[jd] = __builtin_amdgcn_mfma_f32_16x16x16f16(vf, pf, ACC[jd], 0, 0, 0); \
            }                                                                  \
        }                                                                      \
    } while (0)

// stage K tile (128 keys x 64 d) + V^T tile (64 d x 128 keys) into buffer BUF
#define STAGE_KV(BUF, KT)                                                      \
    do {                                                                       \
        _Pragma("unroll")                                                      \
        for (int i_ = 0; i_ < 4; i_++) {                                       \
            int rows8_ = wave * 32 + i_ * 8;                                   \
            gll16(Kh + (size_t)((KT) * 128 + rows8_ + lrow) * HD + (lg ^ lrow) * 8, \
                  &Ks[BUF][rows8_ * 64]);                                      \
        }                                                                      \
        _Pragma("unroll")                                                      \
        for (int i_ = 0; i_ < 4; i_++) {                                       \
            int rows4_ = wave * 16 + i_ * 4;                                   \
            int row_ = rows4_ + (lane >> 4);                                   \
            int g_ = (lane & 15) ^ (row_ & 15);                                \
            gll16(Vh + (size_t)row_ * SEQ + (KT) * 128 + g_ * 8,               \
                  &Vs[BUF][rows4_ * 128]);                                     \
        }                                                                      \
    } while (0)

__global__ __launch_bounds__(256, 2)
void attn6_kernel(const unsigned short* __restrict__ Q,
                  const unsigned short* __restrict__ K,
                  const unsigned short* __restrict__ V,
                  unsigned short* __restrict__ O)
{
    __shared__ __align__(16) unsigned short Ks[2][128 * 64];  // [key][d] swizzled bf16
    __shared__ __align__(16) unsigned short Vs[2][64 * 128];  // [d][key] swizzled f16

    const int t = threadIdx.x;
    const int wave = t >> 6, lane = t & 63;
    const int lm = lane & 15, lq = lane >> 4;
    const int bh = blockIdx.y;
    const int jlo = blockIdx.x, jhi = 31 - jlo;
    const int qlo = jlo * 64 + wave * 16 + lm;
    const int qhi = jhi * 64 + wave * 16 + lm;

    const unsigned short* Qh = Q + (size_t)bh * SEQ * HD;
    const unsigned short* Kh = K + (size_t)bh * SEQ * HD;
    const unsigned short* Vh = V + (size_t)bh * HD * SEQ;  // [d][s]

    short8 bq_lo[2], bq_hi[2];
    bq_lo[0] = *(const short8*)(Qh + (size_t)qlo * HD + lq * 8);
    bq_lo[1] = *(const short8*)(Qh + (size_t)qlo * HD + 32 + lq * 8);
    bq_hi[0] = *(const short8*)(Qh + (size_t)qhi * HD + lq * 8);
    bq_hi[1] = *(const short8*)(Qh + (size_t)qhi * HD + 32 + lq * 8);

    floatx4 acc_lo[4] = {}, acc_hi[4] = {};
    float l_lo = 0.f, l_hi = 0.f;
    const float kA = 0.04508422002778011f;  // log2(e)/32

    const int lrow = lane >> 3, lg = lane & 7;
    const int kt_min = jlo >> 1;
    const int kthi_min = 15 - kt_min;

    // prologue: stage tile kt=15 into buffer 0, single full drain
    STAGE_KV(0, 15);
    __syncthreads();

    for (int kt = 15; kt >= kt_min; kt--) {
        const int cb = (15 - kt) & 1;
        // issue next tile's stage BEFORE compute (latency hides under MFMA)
        if (kt - 1 >= kt_min) STAGE_KV(cb ^ 1, kt - 1);

        const unsigned short* Ksb = &Ks[cb][0];
        const __fp16* Vsb = (const __fp16*)&Vs[cb][0];

        PROCESS_Q(qlo, bq_lo, acc_lo, l_lo, (kt == kt_min), kt);
        if (kt >= kthi_min)
            PROCESS_Q(qhi, bq_hi, acc_hi, l_hi, (kt == kthi_min), kt);

        // one drain point: implicit vmcnt(0) (next stage landed) + barrier
        __syncthreads();
    }

    const int b = bh >> 4, h = bh & 15;
    {
        float l = l_lo;
        l += __shfl_xor(l, 16); l += __shfl_xor(l, 32);
        float inv = 1.0f / l;
#pragma unroll
        for (int jd = 0; jd < 4; jd++) {
            bfx4 o;
#pragma unroll
            for (int r = 0; r < 4; r++) o[r] = (short)f2bf(acc_lo[jd][r] * inv);
            *(bfx4*)(O + (size_t)(b * SEQ + qlo) * D_MODEL + h * HD + jd * 16 + lq * 4) = o;
        }
    }
    {
        float l = l_hi;
        l += __shfl_xor(l, 16); l += __shfl_xor(l, 32);
        float inv = 1.0f / l;
#pragma unroll
        for (int jd = 0; jd < 4; jd++) {
            bfx4 o;
#pragma unroll
            for (int r = 0; r < 4; r++) o[r] = (short)f2bf(acc_hi[jd][r] * inv);
            *(bfx4*)(O + (size_t)(b * SEQ + qhi) * D_MODEL + h * HD + jd * 16 + lq * 4) = o;
        }
    }
}

// ---------------------------------------------------------------------------
// Row 2047 is fully masked -> uniform softmax over ALL keys -> mean of V.
// ---------------------------------------------------------------------------
__global__ __launch_bounds__(256, 2)
void row2047_kernel(const unsigned short* __restrict__ V,
                    unsigned short* __restrict__ O)
{
    __shared__ float red[256];
    const int bh = blockIdx.x;
    const int b = bh >> 4, h = bh & 15;
    const int t = threadIdx.x;
    const int d = t & 63, seg = t >> 6;
    const __fp16* Vh = (const __fp16*)V + (size_t)bh * HD * SEQ + (size_t)d * SEQ + seg * 512;
    float s = 0.f;
    for (int i = 0; i < 512; i += 8) {
        h8_t v = *(const h8_t*)(Vh + i);
#pragma unroll
        for (int j = 0; j < 8; j++) s += (float)v[j];
    }
    red[t] = s;
    __syncthreads();
    if (seg == 0) {
        float tot = red[d] + red[64 + d] + red[128 + d] + red[192 + d];
        O[(size_t)(b * SEQ + 2047) * D_MODEL + h * HD + d] = f2bf(tot * (1.f / 2048.f));
    }
}

// ======================= fallback (ws < 72 MiB) kernels =====================
__global__ __launch_bounds__(256, 2)
void gemm_qkv_kernel(const float* __restrict__ A,
                     const float* __restrict__ W0,
                     const float* __restrict__ W1,
                     const float* __restrict__ W2,
                     unsigned short* __restrict__ O0,
                     unsigned short* __restrict__ O1,
                     unsigned short* __restrict__ O2)
{
    const int K = 1024;
    const float* W;
    unsigned short* Out;
    if (blockIdx.z == 0)      { W = W0; Out = O0; }
    else if (blockIdx.z == 1) { W = W1; Out = O1; }
    else                      { W = W2; Out = O2; }

    __shared__ __align__(16) unsigned short As[128 * 64];
    __shared__ __align__(16) unsigned short Bs[128 * 64];

    const int t = threadIdx.x;
    const int wave = t >> 6, lane = t & 63;
    const int lm = lane & 15, lq = lane >> 4;
    const int wrow = (wave >> 1) * 64, wcol = (wave & 1) * 64;
    const int m0 = blockIdx.x * 128, n0 = blockIdx.y * 128;

    floatx4 acc[4][4] = {};

    for (int k0 = 0; k0 < K; k0 += 64) {
        __syncthreads();
#pragma unroll
        for (int rr = 0; rr < 4; rr++) {
            int p = rr * 256 + t;
            int row = p >> 3, g = p & 7;
            const float* pa = A + (size_t)(m0 + row) * K + k0 + g * 8;
            const float* pw = W + (size_t)(n0 + row) * K + k0 + g * 8;
            floatx4 a0 = *(const floatx4*)pa, a1 = *(const floatx4*)(pa + 4);
            floatx4 w0 = *(const floatx4*)pw, w1 = *(const floatx4*)(pw + 4);
            short8 va, vb;
#pragma unroll
            for (int d = 0; d < 4; d++) {
                va[d]     = (short)f2bf(a0[d]);
                va[4 + d] = (short)f2bf(a1[d]);
                vb[d]     = (short)f2bf(w0[d]);
                vb[4 + d] = (short)f2bf(w1[d]);
            }
            int dst = row * 8 + (g ^ (row & 7));
            *(short8*)(As + dst * 8) = va;
            *(short8*)(Bs + dst * 8) = vb;
        }
        __syncthreads();

        short8 af[4][2], bf[4][2];
#pragma unroll
        for (int i = 0; i < 4; i++)
#pragma unroll
            for (int c = 0; c < 2; c++) {
                int ra = wrow + i * 16 + lm;
                int rb = wcol + i * 16 + lm;
                int g = c * 4 + lq;
                af[i][c] = *(const short8*)(As + (ra * 8 + (g ^ (ra & 7))) * 8);
                bf[i][c] = *(const short8*)(Bs + (rb * 8 + (g ^ (rb & 7))) * 8);
            }
#pragma unroll
        for (int i = 0; i < 4; i++)
#pragma unroll
            for (int j = 0; j < 4; j++)
#pragma unroll
                for (int c = 0; c < 2; c++)
                    acc[i][j] = __builtin_amdgcn_mfma_f32_16x16x32_bf16(
                        af[i][c], bf[j][c], acc[i][j], 0, 0, 0);
    }

    const int zi = blockIdx.z;
#pragma unroll
    for (int i = 0; i < 4; i++)
#pragma unroll
        for (int j = 0; j < 4; j++)
#pragma unroll
            for (int r = 0; r < 4; r++) {
                int gm = m0 + wrow + i * 16 + lq * 4 + r;
                int gn = n0 + wcol + j * 16 + lm;
                int b = gm >> 11, s = gm & 2047;
                int h = gn >> 6, d = gn & 63;
                if (zi == 2) {
                    Out[((size_t)(b * NH + h) * HD + d) * SEQ + s] = f2h(acc[i][j][r]);
                } else {
                    Out[((size_t)(b * NH + h) * SEQ + s) * HD + d] = f2bf(acc[i][j][r]);
                }
            }
}

__global__ __launch_bounds__(256, 2)
void gemm_out_kernel(const unsigned short* __restrict__ Abf,
                     const float* __restrict__ W,
                     float* __restrict__ Out)
{
    const int K = 1024;
    __shared__ __align__(16) unsigned short As[128 * 64];
    __shared__ __align__(16) unsigned short Bs[128 * 64];

    const int t = threadIdx.x;
    const int wave = t >> 6, lane = t & 63;
    const int lm = lane & 15, lq = lane >> 4;
    const int wrow = (wave >> 1) * 64, wcol = (wave & 1) * 64;
    const int m0 = blockIdx.x * 128, n0 = blockIdx.y * 128;

    floatx4 acc[4][4] = {};

    for (int k0 = 0; k0 < K; k0 += 64) {
        __syncthreads();
#pragma unroll
        for (int rr = 0; rr < 4; rr++) {
            int p = rr * 256 + t;
            int row = p >> 3, g = p & 7;
            short8 va = *(const short8*)(Abf + (size_t)(m0 + row) * K + k0 + g * 8);
            const float* pw = W + (size_t)(n0 + row) * K + k0 + g * 8;
            floatx4 w0 = *(const floatx4*)pw, w1 = *(const floatx4*)(pw + 4);
            short8 vb;
#pragma unroll
            for (int d = 0; d < 4; d++) {
                vb[d]     = (short)f2bf(w0[d]);
                vb[4 + d] = (short)f2bf(w1[d]);
            }
            int dst = row * 8 + (g ^ (row & 7));
            *(short8*)(As + dst * 8) = va;
            *(short8*)(Bs + dst * 8) = vb;
        }
        __syncthreads();

        short8 af[4][2], bf[4][2];
#pragma unroll
        for (int i = 0; i < 4; i++)
#pragma unroll
            for (int c = 0; c < 2; c++) {
                int ra = wrow + i * 16 + lm;
                int rb = wcol + i * 16 + lm;
                int g = c * 4 + lq;
                af[i][c] = *(const short8*)(As + (ra * 8 + (g ^ (ra & 7))) * 8);
                bf[i][c] = *(const short8*)(Bs + (rb * 8 + (g ^ (rb & 7))) * 8);
            }
#pragma unroll
        for (int i = 0; i < 4; i++)
#pragma unroll
            for (int j = 0; j < 4; j++)
#pragma unroll
                for (int c = 0; c < 2; c++)
                    acc[i][j] = __builtin_amdgcn_mfma_f32_16x16x32_bf16(
                        af[i][c], bf[j][c], acc[i][j], 0, 0, 0);
    }

#pragma unroll
    for (int i = 0; i < 4; i++)
#pragma unroll
        for (int j = 0; j < 4; j++)
#pragma unroll
            for (int r = 0; r < 4; r++) {
                int gm = m0 + wrow + i * 16 + lq * 4 + r;
                int gn = n0 + wcol + j * 16 + lm;
                Out[(size_t)gm * D_MODEL + gn] = acc[i][j][r];
            }
}

extern "C" void kernel_launch(void* const* d_in, const int* in_sizes, int n_in,
                              void* d_out, int out_size, void* d_ws, size_t ws_size,
                              hipStream_t stream) {
    const float* x  = (const float*)d_in[0];
    const float* wq = (const float*)d_in[1];
    const float* wk = (const float*)d_in[2];
    const float* wv = (const float*)d_in[3];
    const float* wo = (const float*)d_in[4];

    unsigned short* ws = (unsigned short*)d_ws;
    const bool fast = ws_size >= (size_t)36 * 1024 * 1024 * 2;  // 72 MiB

    if (fast) {
        unsigned short* xbf  = ws;                     // 8M elems; reused as Ob
        unsigned short* wqkv = ws + (size_t)ELEMS;     // 3M
        unsigned short* wobf = ws + (size_t)ELEMS + 3 * WELEMS;  // 1M
        unsigned short* Qb   = ws + (size_t)ELEMS + 4 * WELEMS;  // 8M
        unsigned short* Kb   = Qb + ELEMS;
        unsigned short* Vb   = Kb + ELEMS;
        unsigned short* Ob   = xbf;                    // x_bf dead after QKV GEMM

        cvt_kernel<<<6144, 256, 0, stream>>>(x, wq, wk, wv, wo, xbf, wqkv, wobf);
        gemm_qkv2_kernel<<<dim3(64, 12), 256, 0, stream>>>(xbf, wqkv, Qb, Kb, Vb);
        attn6_kernel<<<dim3(16, BATCH * NH), 256, 0, stream>>>(Qb, Kb, Vb, Ob);
        row2047_kernel<<<BATCH * NH, 256, 0, stream>>>(Vb, Ob);
        gemm_out2_kernel<<<dim3(64, 4), 256, 0, stream>>>(Ob, wobf, (float*)d_out);
    } else {
        unsigned short* Qb = ws;
        unsigned short* Kb = Qb + ELEMS;
        unsigned short* Vb = Kb + ELEMS;
        unsigned short* Ob = Vb + ELEMS;

        gemm_qkv_kernel<<<dim3(64, 8, 3), 256, 0, stream>>>(x, wq, wk, wv, Qb, Kb, Vb);
        attn6_kernel<<<dim3(16, BATCH * NH), 256, 0, stream>>>(Qb, Kb, Vb, Ob);
        row2047_kernel<<<BATCH * NH, 256, 0, stream>>>(Vb, Ob);
        gemm_out_kernel<<<dim3(64, 8), 256, 0, stream>>>(Ob, wo, (float*)d_out);
    }
}

// Round 3
// 302.287 us; speedup vs baseline: 1.1297x; 1.1146x over previous
//
#include <hip/hip_runtime.h>
#include <hip/hip_bf16.h>

typedef __attribute__((ext_vector_type(8))) short short8;
typedef __attribute__((ext_vector_type(4))) short bfx4;
typedef __attribute__((ext_vector_type(4))) float floatx4;
typedef __attribute__((ext_vector_type(4))) __fp16 h4_t;
typedef __attribute__((ext_vector_type(2))) __fp16 h2_t;
typedef __attribute__((ext_vector_type(8))) __fp16 h8_t;

#define BATCH 4
#define SEQ 2048
#define D_MODEL 1024
#define NH 16
#define HD 64
#define ELEMS 8388608   // B*S*D = 4*2048*1024
#define WELEMS 1048576  // 1024*1024

// fp32 -> bf16 round-to-nearest-even
__device__ __forceinline__ unsigned short f2bf(float f) {
    union { float f; unsigned u; } x; x.f = f;
    unsigned r = x.u + 0x7FFFu + ((x.u >> 16) & 1u);
    return (unsigned short)(r >> 16);
}
__device__ __forceinline__ unsigned short f2h(float f) {
    union { __fp16 h; unsigned short u; } x;
    x.h = (__fp16)f;
    return x.u;
}

#if __has_builtin(__builtin_amdgcn_exp2f)
__device__ __forceinline__ float fexp2(float x) { return __builtin_amdgcn_exp2f(x); }
#else
__device__ __forceinline__ float fexp2(float x) { return exp2f(x); }
#endif

// async global->LDS, 16B per lane; HW dest = wave-uniform base + lane*16
__device__ __forceinline__ void gll16(const void* g, const void* l) {
    __builtin_amdgcn_global_load_lds(
        (const __attribute__((address_space(1))) void*)g,
        (__attribute__((address_space(3))) void*)l,
        16, 0, 0);
}

// NOTE (R1/R2 post-mortems):
//  - R1: 8-phase 256^2 counted-vmcnt GEMM port regressed (both gemm8 ~200us
//    combined; even QKV >= 100us >> m201 rate). Schedule port deficient.
//  - R2: double-buffered attn (stage-before-compute) regressed 122.6->141.6us:
//    compiler inserts s_waitcnt vmcnt(0) before the first ds_read (cannot
//    prove LDS non-aliasing with in-flight global_load_lds), serializing the
//    stage AHEAD of compute. Do not software-pipeline global_load_lds at HIP
//    source level in these kernels.
//  - R3: stay in the proven 2-barrier structure; use 128x128 tiles (m103
//    tile-space: 128^2=912 TF > 128x256=823 TF; 32KB LDS -> ~5 blocks/CU
//    cross-block TLP hides the per-K-step drain).

// ---------------------------------------------------------------------------
// cvt: x (8M), wq|wk|wv (3M, concatenated), wo (1M) fp32 -> bf16
// ---------------------------------------------------------------------------
__global__ __launch_bounds__(256)
void cvt_kernel(const float* __restrict__ x,  const float* __restrict__ wq,
                const float* __restrict__ wk, const float* __restrict__ wv,
                const float* __restrict__ wo,
                unsigned short* __restrict__ xbf,
                unsigned short* __restrict__ wqkv,
                unsigned short* __restrict__ wobf)
{
    size_t idx = ((size_t)blockIdx.x * 256 + threadIdx.x) * 8;
    const float* src; unsigned short* dst; size_t off;
    if (idx < (size_t)ELEMS)                    { src = x;  dst = xbf;             off = idx; }
    else if (idx < (size_t)ELEMS + WELEMS)      { src = wq; dst = wqkv;            off = idx - ELEMS; }
    else if (idx < (size_t)ELEMS + 2 * WELEMS)  { src = wk; dst = wqkv + WELEMS;   off = idx - ELEMS - WELEMS; }
    else if (idx < (size_t)ELEMS + 3 * WELEMS)  { src = wv; dst = wqkv + 2*WELEMS; off = idx - ELEMS - 2*WELEMS; }
    else                                        { src = wo; dst = wobf;            off = idx - ELEMS - 3*WELEMS; }
    floatx4 a = *(const floatx4*)(src + off);
    floatx4 b = *(const floatx4*)(src + off + 4);
    short8 v;
#pragma unroll
    for (int d = 0; d < 4; d++) { v[d] = (short)f2bf(a[d]); v[4+d] = (short)f2bf(b[d]); }
    *(short8*)(dst + off) = v;
}

// ---------------------------------------------------------------------------
// QKV GEMM, 128x128 tile: A=x_bf [8192,1024], B=wqkv_bf [3072,1024] (NT),
// both staged via global_load_lds with inverse-XOR-swizzled source.
// BK=64, 32 KiB LDS -> ~5 blocks/CU residency. Grid (64,24)=1536 blocks.
// Epilogue scatters Q/K/V (z uniform per block since 1024%128==0).
// ---------------------------------------------------------------------------
__global__ __launch_bounds__(256, 2)
void gemm_qkv3_kernel(const unsigned short* __restrict__ A,
                      const unsigned short* __restrict__ B,
                      unsigned short* __restrict__ Qb,
                      unsigned short* __restrict__ Kb,
                      unsigned short* __restrict__ Vb)
{
    __shared__ __align__(16) unsigned short As[128 * 64];
    __shared__ __align__(16) unsigned short Bs[128 * 64];

    const int t = threadIdx.x;
    const int wave = t >> 6, lane = t & 63;
    const int lm = lane & 15, lq = lane >> 4;
    const int wrow = (wave >> 1) * 64, wcol = (wave & 1) * 64;
    const int m0 = blockIdx.x * 128, n0 = blockIdx.y * 128;
    const int lrow = lane >> 3, lg = lane & 7;
    const int gsw = lg ^ lrow;

    floatx4 acc[4][4] = {};

    for (int k0 = 0; k0 < 1024; k0 += 64) {
        __syncthreads();
#pragma unroll
        for (int i = 0; i < 4; i++) {
            int rows8 = wave * 32 + i * 8;
            gll16(A + (size_t)(m0 + rows8 + lrow) * 1024 + k0 + gsw * 8, As + rows8 * 64);
            gll16(B + (size_t)(n0 + rows8 + lrow) * 1024 + k0 + gsw * 8, Bs + rows8 * 64);
        }
        __syncthreads();

#pragma unroll
        for (int c = 0; c < 2; c++) {
            short8 af[4], bfr[4];
#pragma unroll
            for (int i = 0; i < 4; i++) {
                int ra = wrow + i * 16 + lm;
                int g = c * 4 + lq;
                af[i] = *(const short8*)(As + (ra * 8 + (g ^ (ra & 7))) * 8);
            }
#pragma unroll
            for (int j = 0; j < 4; j++) {
                int rb = wcol + j * 16 + lm;
                int g = c * 4 + lq;
                bfr[j] = *(const short8*)(Bs + (rb * 8 + (g ^ (rb & 7))) * 8);
            }
#pragma unroll
            for (int i = 0; i < 4; i++)
#pragma unroll
                for (int j = 0; j < 4; j++)
                    acc[i][j] = __builtin_amdgcn_mfma_f32_16x16x32_bf16(
                        af[i], bfr[j], acc[i][j], 0, 0, 0);
        }
    }

    const int z = n0 >> 10;   // 0=Q 1=K 2=V, uniform per block
#pragma unroll
    for (int i = 0; i < 4; i++)
#pragma unroll
        for (int j = 0; j < 4; j++)
#pragma unroll
            for (int r = 0; r < 4; r++) {
                int gm = m0 + wrow + i * 16 + lq * 4 + r;
                int gn = n0 + wcol + j * 16 + lm;
                int nl = gn & 1023, h = nl >> 6, d = nl & 63;
                int b = gm >> 11, s = gm & 2047;
                float v = acc[i][j][r];
                size_t bh = (size_t)(b * NH + h);
                if (z == 0)      Qb[(bh * SEQ + s) * HD + d] = f2bf(v);
                else if (z == 1) Kb[(bh * SEQ + s) * HD + d] = f2bf(v);
                else             Vb[(bh * HD + d) * SEQ + s] = f2h(v);
            }
}

// ---------------------------------------------------------------------------
// Output projection, 128x128 tile: A=Ob bf16 [8192,1024], B=wo_bf [1024,1024]
// -> fp32. Grid (64,8)=512 blocks (vs 256 at 128x256: was 1 block/CU with
// zero cross-block overlap -> the latency exposed; 512 blocks + 32KB LDS
// gives multi-block residency).
// ---------------------------------------------------------------------------
__global__ __launch_bounds__(256, 2)
void gemm_out3_kernel(const unsigned short* __restrict__ A,
                      const unsigned short* __restrict__ B,
                      float* __restrict__ Out)
{
    __shared__ __align__(16) unsigned short As[128 * 64];
    __shared__ __align__(16) unsigned short Bs[128 * 64];

    const int t = threadIdx.x;
    const int wave = t >> 6, lane = t & 63;
    const int lm = lane & 15, lq = lane >> 4;
    const int wrow = (wave >> 1) * 64, wcol = (wave & 1) * 64;
    const int m0 = blockIdx.x * 128, n0 = blockIdx.y * 128;
    const int lrow = lane >> 3, lg = lane & 7;
    const int gsw = lg ^ lrow;

    floatx4 acc[4][4] = {};

    for (int k0 = 0; k0 < 1024; k0 += 64) {
        __syncthreads();
#pragma unroll
        for (int i = 0; i < 4; i++) {
            int rows8 = wave * 32 + i * 8;
            gll16(A + (size_t)(m0 + rows8 + lrow) * 1024 + k0 + gsw * 8, As + rows8 * 64);
            gll16(B + (size_t)(n0 + rows8 + lrow) * 1024 + k0 + gsw * 8, Bs + rows8 * 64);
        }
        __syncthreads();

#pragma unroll
        for (int c = 0; c < 2; c++) {
            short8 af[4], bfr[4];
#pragma unroll
            for (int i = 0; i < 4; i++) {
                int ra = wrow + i * 16 + lm;
                int g = c * 4 + lq;
                af[i] = *(const short8*)(As + (ra * 8 + (g ^ (ra & 7))) * 8);
            }
#pragma unroll
            for (int j = 0; j < 4; j++) {
                int rb = wcol + j * 16 + lm;
                int g = c * 4 + lq;
                bfr[j] = *(const short8*)(Bs + (rb * 8 + (g ^ (rb & 7))) * 8);
            }
#pragma unroll
            for (int i = 0; i < 4; i++)
#pragma unroll
                for (int j = 0; j < 4; j++)
                    acc[i][j] = __builtin_amdgcn_mfma_f32_16x16x32_bf16(
                        af[i], bfr[j], acc[i][j], 0, 0, 0);
        }
    }

#pragma unroll
    for (int i = 0; i < 4; i++)
#pragma unroll
        for (int j = 0; j < 4; j++)
#pragma unroll
            for (int r = 0; r < 4; r++) {
                int gm = m0 + wrow + i * 16 + lq * 4 + r;
                int gn = n0 + wcol + j * 16 + lm;
                Out[(size_t)gm * D_MODEL + gn] = acc[i][j][r];
            }
}

// ---------------------------------------------------------------------------
// Flash attention v5 (round-0 proven version, 122.6 us): balanced paired
// q-tiles (j,31-j), no-max softmax, streamed sub-tiles, single-buffered K/V
// with per-tile drain. Q,K bf16 [b,h,s,d]; V f16 [b,h,d,s]; O bf16 [b,s,1024].
// Row 2047 (l=0) fixed by row2047_kernel afterwards.
// ---------------------------------------------------------------------------
#define PROCESS_Q(QI, BQ, ACC, LACC, DOMASK, KT)                               \
    do {                                                                       \
        _Pragma("unroll")                                                      \
        for (int jt = 0; jt < 8; jt++) {                                       \
            floatx4 sc = {};                                                   \
            _Pragma("unroll")                                                  \
            for (int c = 0; c < 2; c++) {                                      \
                int row_ = jt * 16 + lm;                                       \
                int g_ = c * 4 + lq;                                           \
                short8 kf = *(const short8*)(Ks + (row_ * 8 + (g_ ^ (row_ & 7))) * 8); \
                sc = __builtin_amdgcn_mfma_f32_16x16x32_bf16(kf, BQ[c], sc, 0, 0, 0); \
            }                                                                  \
            if (DOMASK) {                                                      \
                _Pragma("unroll")                                              \
                for (int r = 0; r < 4; r++) {                                  \
                    int kj = (KT) * 128 + jt * 16 + lq * 4 + r;                \
                    if (!(kj > (QI))) sc[r] = -3.2e10f;                        \
                }                                                              \
            }                                                                  \
            float p0 = fexp2(sc[0] * kA), p1 = fexp2(sc[1] * kA);              \
            float p2 = fexp2(sc[2] * kA), p3 = fexp2(sc[3] * kA);              \
            LACC += (p0 + p1) + (p2 + p3);                                     \
            h2_t a01 = __builtin_amdgcn_cvt_pkrtz(p0, p1);                     \
            h2_t a23 = __builtin_amdgcn_cvt_pkrtz(p2, p3);                     \
            h4_t pf;                                                           \
            pf[0] = a01[0]; pf[1] = a01[1]; pf[2] = a23[0]; pf[3] = a23[1];    \
            _Pragma("unroll")                                                  \
            for (int jd = 0; jd < 4; jd++) {                                   \
                int rowv_ = jd * 16 + lm;                                      \
                int g16_ = jt * 2 + (lq >> 1);                                 \
                int slot_ = rowv_ * 16 + (g16_ ^ lm);                          \
                h4_t vf = *(const h4_t*)((const __fp16*)Vs + slot_ * 8 + (lq & 1) * 4); \
                ACC[jd] = __builtin_amdgcn_mfma_f32_16x16x16f16(vf, pf, ACC[jd], 0, 0, 0); \
            }                                                                  \
        }                                                                      \
    } while (0)

__global__ __launch_bounds__(256, 2)
void attn5_kernel(const unsigned short* __restrict__ Q,
                  const unsigned short* __restrict__ K,
                  const unsigned short* __restrict__ V,
                  unsigned short* __restrict__ O)
{
    __shared__ __align__(16) unsigned short Ks[128 * 64];  // [key][d] swizzled bf16
    __shared__ __align__(16) unsigned short Vs[64 * 128];  // [d][key] swizzled f16

    const int t = threadIdx.x;
    const int wave = t >> 6, lane = t & 63;
    const int lm = lane & 15, lq = lane >> 4;
    const int bh = blockIdx.y;
    const int jlo = blockIdx.x, jhi = 31 - jlo;
    const int qlo = jlo * 64 + wave * 16 + lm;
    const int qhi = jhi * 64 + wave * 16 + lm;

    const unsigned short* Qh = Q + (size_t)bh * SEQ * HD;
    const unsigned short* Kh = K + (size_t)bh * SEQ * HD;
    const unsigned short* Vh = V + (size_t)bh * HD * SEQ;  // [d][s]

    short8 bq_lo[2], bq_hi[2];
    bq_lo[0] = *(const short8*)(Qh + (size_t)qlo * HD + lq * 8);
    bq_lo[1] = *(const short8*)(Qh + (size_t)qlo * HD + 32 + lq * 8);
    bq_hi[0] = *(const short8*)(Qh + (size_t)qhi * HD + lq * 8);
    bq_hi[1] = *(const short8*)(Qh + (size_t)qhi * HD + 32 + lq * 8);

    floatx4 acc_lo[4] = {}, acc_hi[4] = {};
    float l_lo = 0.f, l_hi = 0.f;
    const float kA = 0.04508422002778011f;  // log2(e)/32

    const int lrow = lane >> 3, lg = lane & 7;
    const int kt_min = jlo >> 1;
    const int kthi_min = 15 - kt_min;

    for (int kt = 15; kt >= kt_min; kt--) {
        __syncthreads();
        // K tile: 128 keys x 64 d
#pragma unroll
        for (int i = 0; i < 4; i++) {
            int rows8 = wave * 32 + i * 8;
            gll16(Kh + (size_t)(kt * 128 + rows8 + lrow) * HD + (lg ^ lrow) * 8,
                  Ks + rows8 * 64);
        }
        // V^T tile: 64 d x 128 keys
#pragma unroll
        for (int i = 0; i < 4; i++) {
            int rows4 = wave * 16 + i * 4;
            int row = rows4 + (lane >> 4);
            int g = (lane & 15) ^ (row & 15);
            gll16(Vh + (size_t)row * SEQ + kt * 128 + g * 8, Vs + rows4 * 128);
        }
        __syncthreads();

        PROCESS_Q(qlo, bq_lo, acc_lo, l_lo, (kt == kt_min), kt);
        if (kt >= kthi_min)
            PROCESS_Q(qhi, bq_hi, acc_hi, l_hi, (kt == kthi_min), kt);
    }

    const int b = bh >> 4, h = bh & 15;
    {
        float l = l_lo;
        l += __shfl_xor(l, 16); l += __shfl_xor(l, 32);
        float inv = 1.0f / l;
#pragma unroll
        for (int jd = 0; jd < 4; jd++) {
            bfx4 o;
#pragma unroll
            for (int r = 0; r < 4; r++) o[r] = (short)f2bf(acc_lo[jd][r] * inv);
            *(bfx4*)(O + (size_t)(b * SEQ + qlo) * D_MODEL + h * HD + jd * 16 + lq * 4) = o;
        }
    }
    {
        float l = l_hi;
        l += __shfl_xor(l, 16); l += __shfl_xor(l, 32);
        float inv = 1.0f / l;
#pragma unroll
        for (int jd = 0; jd < 4; jd++) {
            bfx4 o;
#pragma unroll
            for (int r = 0; r < 4; r++) o[r] = (short)f2bf(acc_hi[jd][r] * inv);
            *(bfx4*)(O + (size_t)(b * SEQ + qhi) * D_MODEL + h * HD + jd * 16 + lq * 4) = o;
        }
    }
}

// ---------------------------------------------------------------------------
// Row 2047 is fully masked -> uniform softmax over ALL keys -> mean of V.
// ---------------------------------------------------------------------------
__global__ __launch_bounds__(256, 2)
void row2047_kernel(const unsigned short* __restrict__ V,
                    unsigned short* __restrict__ O)
{
    __shared__ float red[256];
    const int bh = blockIdx.x;
    const int b = bh >> 4, h = bh & 15;
    const int t = threadIdx.x;
    const int d = t & 63, seg = t >> 6;
    const __fp16* Vh = (const __fp16*)V + (size_t)bh * HD * SEQ + (size_t)d * SEQ + seg * 512;
    float s = 0.f;
    for (int i = 0; i < 512; i += 8) {
        h8_t v = *(const h8_t*)(Vh + i);
#pragma unroll
        for (int j = 0; j < 8; j++) s += (float)v[j];
    }
    red[t] = s;
    __syncthreads();
    if (seg == 0) {
        float tot = red[d] + red[64 + d] + red[128 + d] + red[192 + d];
        O[(size_t)(b * SEQ + 2047) * D_MODEL + h * HD + d] = f2bf(tot * (1.f / 2048.f));
    }
}

// ======================= fallback (ws < 72 MiB) kernels =====================
__global__ __launch_bounds__(256, 2)
void gemm_qkv_kernel(const float* __restrict__ A,
                     const float* __restrict__ W0,
                     const float* __restrict__ W1,
                     const float* __restrict__ W2,
                     unsigned short* __restrict__ O0,
                     unsigned short* __restrict__ O1,
                     unsigned short* __restrict__ O2)
{
    const int K = 1024;
    const float* W;
    unsigned short* Out;
    if (blockIdx.z == 0)      { W = W0; Out = O0; }
    else if (blockIdx.z == 1) { W = W1; Out = O1; }
    else                      { W = W2; Out = O2; }

    __shared__ __align__(16) unsigned short As[128 * 64];
    __shared__ __align__(16) unsigned short Bs[128 * 64];

    const int t = threadIdx.x;
    const int wave = t >> 6, lane = t & 63;
    const int lm = lane & 15, lq = lane >> 4;
    const int wrow = (wave >> 1) * 64, wcol = (wave & 1) * 64;
    const int m0 = blockIdx.x * 128, n0 = blockIdx.y * 128;

    floatx4 acc[4][4] = {};

    for (int k0 = 0; k0 < K; k0 += 64) {
        __syncthreads();
#pragma unroll
        for (int rr = 0; rr < 4; rr++) {
            int p = rr * 256 + t;
            int row = p >> 3, g = p & 7;
            const float* pa = A + (size_t)(m0 + row) * K + k0 + g * 8;
            const float* pw = W + (size_t)(n0 + row) * K + k0 + g * 8;
            floatx4 a0 = *(const floatx4*)pa, a1 = *(const floatx4*)(pa + 4);
            floatx4 w0 = *(const floatx4*)pw, w1 = *(const floatx4*)(pw + 4);
            short8 va, vb;
#pragma unroll
            for (int d = 0; d < 4; d++) {
                va[d]     = (short)f2bf(a0[d]);
                va[4 + d] = (short)f2bf(a1[d]);
                vb[d]     = (short)f2bf(w0[d]);
                vb[4 + d] = (short)f2bf(w1[d]);
            }
            int dst = row * 8 + (g ^ (row & 7));
            *(short8*)(As + dst * 8) = va;
            *(short8*)(Bs + dst * 8) = vb;
        }
        __syncthreads();

        short8 af[4][2], bf[4][2];
#pragma unroll
        for (int i = 0; i < 4; i++)
#pragma unroll
            for (int c = 0; c < 2; c++) {
                int ra = wrow + i * 16 + lm;
                int rb = wcol + i * 16 + lm;
                int g = c * 4 + lq;
                af[i][c] = *(const short8*)(As + (ra * 8 + (g ^ (ra & 7))) * 8);
                bf[i][c] = *(const short8*)(Bs + (rb * 8 + (g ^ (rb & 7))) * 8);
            }
#pragma unroll
        for (int i = 0; i < 4; i++)
#pragma unroll
            for (int j = 0; j < 4; j++)
#pragma unroll
                for (int c = 0; c < 2; c++)
                    acc[i][j] = __builtin_amdgcn_mfma_f32_16x16x32_bf16(
                        af[i][c], bf[j][c], acc[i][j], 0, 0, 0);
    }

    const int zi = blockIdx.z;
#pragma unroll
    for (int i = 0; i < 4; i++)
#pragma unroll
        for (int j = 0; j < 4; j++)
#pragma unroll
            for (int r = 0; r < 4; r++) {
                int gm = m0 + wrow + i * 16 + lq * 4 + r;
                int gn = n0 + wcol + j * 16 + lm;
                int b = gm >> 11, s = gm & 2047;
                int h = gn >> 6, d = gn & 63;
                if (zi == 2) {
                    Out[((size_t)(b * NH + h) * HD + d) * SEQ + s] = f2h(acc[i][j][r]);
                } else {
                    Out[((size_t)(b * NH + h) * SEQ + s) * HD + d] = f2bf(acc[i][j][r]);
                }
            }
}

__global__ __launch_bounds__(256, 2)
void gemm_out_kernel(const unsigned short* __restrict__ Abf,
                     const float* __restrict__ W,
                     float* __restrict__ Out)
{
    const int K = 1024;
    __shared__ __align__(16) unsigned short As[128 * 64];
    __shared__ __align__(16) unsigned short Bs[128 * 64];

    const int t = threadIdx.x;
    const int wave = t >> 6, lane = t & 63;
    const int lm = lane & 15, lq = lane >> 4;
    const int wrow = (wave >> 1) * 64, wcol = (wave & 1) * 64;
    const int m0 = blockIdx.x * 128, n0 = blockIdx.y * 128;

    floatx4 acc[4][4] = {};

    for (int k0 = 0; k0 < K; k0 += 64) {
        __syncthreads();
#pragma unroll
        for (int rr = 0; rr < 4; rr++) {
            int p = rr * 256 + t;
            int row = p >> 3, g = p & 7;
            short8 va = *(const short8*)(Abf + (size_t)(m0 + row) * K + k0 + g * 8);
            const float* pw = W + (size_t)(n0 + row) * K + k0 + g * 8;
            floatx4 w0 = *(const floatx4*)pw, w1 = *(const floatx4*)(pw + 4);
            short8 vb;
#pragma unroll
            for (int d = 0; d < 4; d++) {
                vb[d]     = (short)f2bf(w0[d]);
                vb[4 + d] = (short)f2bf(w1[d]);
            }
            int dst = row * 8 + (g ^ (row & 7));
            *(short8*)(As + dst * 8) = va;
            *(short8*)(Bs + dst * 8) = vb;
        }
        __syncthreads();

        short8 af[4][2], bf[4][2];
#pragma unroll
        for (int i = 0; i < 4; i++)
#pragma unroll
            for (int c = 0; c < 2; c++) {
                int ra = wrow + i * 16 + lm;
                int rb = wcol + i * 16 + lm;
                int g = c * 4 + lq;
                af[i][c] = *(const short8*)(As + (ra * 8 + (g ^ (ra & 7))) * 8);
                bf[i][c] = *(const short8*)(Bs + (rb * 8 + (g ^ (rb & 7))) * 8);
            }
#pragma unroll
        for (int i = 0; i < 4; i++)
#pragma unroll
            for (int j = 0; j < 4; j++)
#pragma unroll
                for (int c = 0; c < 2; c++)
                    acc[i][j] = __builtin_amdgcn_mfma_f32_16x16x32_bf16(
                        af[i][c], bf[j][c], acc[i][j], 0, 0, 0);
    }

#pragma unroll
    for (int i = 0; i < 4; i++)
#pragma unroll
        for (int j = 0; j < 4; j++)
#pragma unroll
            for (int r = 0; r < 4; r++) {
                int gm = m0 + wrow + i * 16 + lq * 4 + r;
                int gn = n0 + wcol + j * 16 + lm;
                Out[(size_t)gm * D_MODEL + gn] = acc[i][j][r];
            }
}

extern "C" void kernel_launch(void* const* d_in, const int* in_sizes, int n_in,
                              void* d_out, int out_size, void* d_ws, size_t ws_size,
                              hipStream_t stream) {
    const float* x  = (const float*)d_in[0];
    const float* wq = (const float*)d_in[1];
    const float* wk = (const float*)d_in[2];
    const float* wv = (const float*)d_in[3];
    const float* wo = (const float*)d_in[4];

    unsigned short* ws = (unsigned short*)d_ws;
    const bool fast = ws_size >= (size_t)36 * 1024 * 1024 * 2;  // 72 MiB

    if (fast) {
        unsigned short* xbf  = ws;                     // 8M elems; reused as Ob
        unsigned short* wqkv = ws + (size_t)ELEMS;     // 3M
        unsigned short* wobf = ws + (size_t)ELEMS + 3 * WELEMS;  // 1M
        unsigned short* Qb   = ws + (size_t)ELEMS + 4 * WELEMS;  // 8M
        unsigned short* Kb   = Qb + ELEMS;
        unsigned short* Vb   = Kb + ELEMS;
        unsigned short* Ob   = xbf;                    // x_bf dead after QKV GEMM

        cvt_kernel<<<6144, 256, 0, stream>>>(x, wq, wk, wv, wo, xbf, wqkv, wobf);
        gemm_qkv3_kernel<<<dim3(64, 24), 256, 0, stream>>>(xbf, wqkv, Qb, Kb, Vb);
        attn5_kernel<<<dim3(16, BATCH * NH), 256, 0, stream>>>(Qb, Kb, Vb, Ob);
        row2047_kernel<<<BATCH * NH, 256, 0, stream>>>(Vb, Ob);
        gemm_out3_kernel<<<dim3(64, 8), 256, 0, stream>>>(Ob, wobf, (float*)d_out);
    } else {
        unsigned short* Qb = ws;
        unsigned short* Kb = Qb + ELEMS;
        unsigned short* Vb = Kb + ELEMS;
        unsigned short* Ob = Vb + ELEMS;

        gemm_qkv_kernel<<<dim3(64, 8, 3), 256, 0, stream>>>(x, wq, wk, wv, Qb, Kb, Vb);
        attn5_kernel<<<dim3(16, BATCH * NH), 256, 0, stream>>>(Qb, Kb, Vb, Ob);
        row2047_kernel<<<BATCH * NH, 256, 0, stream>>>(Vb, Ob);
        gemm_out_kernel<<<dim3(64, 8), 256, 0, stream>>>(Ob, wo, (float*)d_out);
    }
}